// Round 3
// baseline (308.108 us; speedup 1.0000x reference)
//
#include <hip/hip_runtime.h>

// pred, target: [32,1,1024,1024] f32 -> scalar f32 = mean((softplus(p)-p*t)*w),
// w = 0.1 on 5x5 morphological gradient of binarized target, gated on
// cond = (t.max()==1 && t.min()==0).
//
// R3 restructure (2nd resubmit; R1/R2 benches were infra failures, never ran):
//   K1 bbl_bits: pure-stream target -> packed ballot bit-words (4 MB) + min/max.
//                No LDS, no barriers, max MLP. Interleaved layout preserved:
//                word w = it*4+m holds cols 256*it + 4*lane + m at bit `lane`.
//   K2 bbl_loss: band kernel; phase-1 preamble now reads 4.6 KB of bits/block
//                (was 147 KB raw target + halo re-read), morphology in LDS
//                (rows padded 16->17 words to kill 4-way bank aliasing),
//                then streams pred with 4 hoisted float4 loads per row.
// Old fused kernel kept as fallback if ws_size < 4 MB + 64 B.

#define IMG     1024
#define BAND    32
#define NBANDS  (IMG / BAND)     // 32
#define NIMG    32
#define WORDS   16               // 1024 cols / 64 bits
#define WPAD    17               // LDS pad: breaks 4-way bank aliasing
#define HALO    2
#define MAXROWS (BAND + 2 * HALO)
#define NROWS   (NIMG * IMG)     // 32768
#define NTOT    33554432.0

typedef unsigned long long u64;

__device__ __forceinline__ unsigned encf(float f) {
    unsigned u = __float_as_uint(f);
    return (u & 0x80000000u) ? ~u : (u | 0x80000000u);
}
__device__ __forceinline__ float decf(unsigned e) {
    unsigned u = (e & 0x80000000u) ? (e & 0x7fffffffu) : ~e;
    return __uint_as_float(u);
}

__global__ void bbl_init(double* dws, unsigned* uws) {
    if (threadIdx.x == 0) {
        dws[0] = 0.0; dws[1] = 0.0;
        uws[0] = 0xFFFFFFFFu;   // running min (encoded)
        uws[1] = 0u;            // running max (encoded)
    }
}

// ---------------- K1: target -> bit-words + global min/max -------------------
__global__ __launch_bounds__(256) void bbl_bits(
        const float* __restrict__ target,
        u64* __restrict__ bits, unsigned* __restrict__ uws) {
    __shared__ unsigned redMn[4], redMx[4];
    const int tid  = threadIdx.x;
    const int lane = tid & 63;
    const int wv   = tid >> 6;                  // 4 waves/block
    const int waveId = blockIdx.x * 4 + wv;
    const int nWaves = gridDim.x * 4;

    float vmin = 3.4e38f, vmax = -3.4e38f;

    for (int row = waveId; row < NROWS; row += nWaves) {
        const float4* rowp = (const float4*)(target + (size_t)row * IMG);
        // 4 independent float4 loads in flight per wave
        float4 v0 = rowp[lane];
        float4 v1 = rowp[64 + lane];
        float4 v2 = rowp[128 + lane];
        float4 v3 = rowp[192 + lane];

        vmin = fminf(vmin, fminf(fminf(v0.x, v0.y), fminf(v0.z, v0.w)));
        vmax = fmaxf(vmax, fmaxf(fmaxf(v0.x, v0.y), fmaxf(v0.z, v0.w)));
        vmin = fminf(vmin, fminf(fminf(v1.x, v1.y), fminf(v1.z, v1.w)));
        vmax = fmaxf(vmax, fmaxf(fmaxf(v1.x, v1.y), fmaxf(v1.z, v1.w)));
        vmin = fminf(vmin, fminf(fminf(v2.x, v2.y), fminf(v2.z, v2.w)));
        vmax = fmaxf(vmax, fmaxf(fmaxf(v2.x, v2.y), fmaxf(v2.z, v2.w)));
        vmin = fminf(vmin, fminf(fminf(v3.x, v3.y), fminf(v3.z, v3.w)));
        vmax = fmaxf(vmax, fmaxf(fmaxf(v3.x, v3.y), fmaxf(v3.z, v3.w)));

        u64 myw = 0ULL;
        #pragma unroll
        for (int it = 0; it < 4; ++it) {
            float4 v = (it == 0) ? v0 : (it == 1) ? v1 : (it == 2) ? v2 : v3;
            u64 b0 = __ballot(v.x > 0.5f);
            u64 b1 = __ballot(v.y > 0.5f);
            u64 b2 = __ballot(v.z > 0.5f);
            u64 b3 = __ballot(v.w > 0.5f);
            if ((lane >> 2) == it) {            // lanes 0..15 pick word = lane
                const int m = lane & 3;
                myw = (m == 0) ? b0 : (m == 1) ? b1 : (m == 2) ? b2 : b3;
            }
        }
        if (lane < 16) bits[(size_t)row * WORDS + lane] = myw;  // 128 B/row
    }

    // min/max reduction: wave shuffles -> LDS -> one atomic pair per block
    for (int off = 32; off > 0; off >>= 1) {
        vmin = fminf(vmin, __shfl_down(vmin, off));
        vmax = fmaxf(vmax, __shfl_down(vmax, off));
    }
    if (lane == 0) { redMn[wv] = encf(vmin); redMx[wv] = encf(vmax); }
    __syncthreads();
    if (tid == 0) {
        unsigned mn = 0xFFFFFFFFu, mx = 0u;
        #pragma unroll
        for (int i = 0; i < 4; ++i) { mn = min(mn, redMn[i]); mx = max(mx, redMx[i]); }
        atomicMin(&uws[0], mn);
        atomicMax(&uws[1], mx);
    }
}

// ---------------- K2: bits -> morphology in LDS; stream pred -> sums ---------
__global__ __launch_bounds__(512) void bbl_loss(
        const float* __restrict__ pred,
        const u64* __restrict__ bits,
        double* __restrict__ dws) {
    __shared__ u64 Bm[MAXROWS][WPAD];   // raw bits, interleaved layout
    __shared__ u64 Vd[BAND][WPAD];      // vertical OR  (dilate, 5 rows)
    __shared__ u64 Ve[BAND][WPAD];      // vertical AND (erode, 5 rows)
    __shared__ u64 Em[BAND][WPAD];      // edge bits
    __shared__ float redS1[8], redSe[8];

    const int tid  = threadIdx.x;
    const int lane = tid & 63;
    const int wid  = tid >> 6;           // 8 waves
    const int img  = blockIdx.x / NBANDS;
    const int r0   = (blockIdx.x % NBANDS) * BAND;
    const int hs   = max(r0 - HALO, 0);
    const int he   = min(r0 + BAND + HALO, IMG);
    const int nLoaded = he - hs;
    const size_t base = (size_t)img * IMG * IMG;

    // ---- 1a: load bit words for band+halo rows (<= 576 u64 = 4.6 KB)
    {
        const u64* gb = bits + ((size_t)img * IMG + hs) * WORDS;
        for (int i = tid; i < nLoaded * WORDS; i += 512)
            Bm[i >> 4][i & 15] = gb[i];
    }
    __syncthreads();

    // ---- 1b: vertical OR/AND over rows gr-2..gr+2 (clamped; skipped rows are
    //          identity, matching -inf/+inf reduce_window padding)
    {
        const int orow = tid >> 4, w = tid & 15;      // 32*16 = 512 = blockDim
        const int gr = r0 + orow;
        const int lo = max(gr - 2, 0), hi = min(gr + 2, IMG - 1);
        u64 vd = 0ULL, ve = ~0ULL;
        for (int g = lo; g <= hi; ++g) { u64 b = Bm[g - hs][w]; vd |= b; ve &= b; }
        Vd[orow][w] = vd; Ve[orow][w] = ve;
    }
    __syncthreads();

    // ---- 1c: horizontal +-2 in interleaved domain; edge = dilate & ~erode
    {
        const int orow = tid >> 4, w = tid & 15;
        const int k = w & 3;
        u64 hd = Vd[orow][w], he_ = Ve[orow][w];
        #pragma unroll
        for (int dd = 0; dd < 4; ++dd) {
            const int delta = (dd < 2) ? dd - 2 : dd - 1;  // -2,-1,1,2
            const int kp = k + delta;
            u64 td, te;
            if (kp >= 0 && kp <= 3) {               // same 256-block, aligned
                td = Vd[orow][w + delta];
                te = Ve[orow][w + delta];
            } else if (kp > 3) {                    // wraps toward next block
                const int wi = w + delta - 4, wn = w + delta;
                u64 nd = (wn <= 15) ? Vd[orow][wn] : 0ULL;   // OOB col: dilate id
                u64 ne = (wn <= 15) ? Ve[orow][wn] : ~0ULL;  // OOB col: erode id
                td = (Vd[orow][wi] >> 1) | (nd << 63);
                te = (Ve[orow][wi] >> 1) | (ne << 63);
            } else {                                // wraps toward prev block
                const int wi = w + delta + 4, wn = w + delta;
                u64 nd = (wn >= 0) ? Vd[orow][wn] : 0ULL;
                u64 ne = (wn >= 0) ? Ve[orow][wn] : ~0ULL;
                td = (Vd[orow][wi] << 1) | (nd >> 63);
                te = (Ve[orow][wi] << 1) | (ne >> 63);
            }
            hd |= td; he_ &= te;
        }
        Em[orow][w] = hd & ~he_;
    }
    __syncthreads();

    // ---- 2: stream pred float4 (4 hoisted loads/row); bits via LDS broadcast
    float s1 = 0.f, se = 0.f;
    for (int orow = wid * 4; orow < wid * 4 + 4; ++orow) {   // 8 waves x 4 rows
        const int gr = r0 + orow, lr = gr - hs;
        const float4* rowp = (const float4*)(pred + base + (size_t)gr * IMG);
        float4 p0 = rowp[lane];
        float4 p1 = rowp[64 + lane];
        float4 p2 = rowp[128 + lane];
        float4 p3 = rowp[192 + lane];
        #pragma unroll
        for (int it = 0; it < 4; ++it) {
            float4 p = (it == 0) ? p0 : (it == 1) ? p1 : (it == 2) ? p2 : p3;
            u64 e0 = Em[orow][it * 4 + 0], e1 = Em[orow][it * 4 + 1];
            u64 e2 = Em[orow][it * 4 + 2], e3 = Em[orow][it * 4 + 3];
            u64 t0 = Bm[lr][it * 4 + 0],   t1 = Bm[lr][it * 4 + 1];
            u64 t2 = Bm[lr][it * 4 + 2],   t3 = Bm[lr][it * 4 + 3];
            float x, l;
            x = p.x;
            l = fmaxf(x, 0.f) + __logf(1.f + __expf(-fabsf(x)))
                - (((t0 >> lane) & 1ULL) ? x : 0.f);
            s1 += l; se += ((e0 >> lane) & 1ULL) ? l : 0.f;
            x = p.y;
            l = fmaxf(x, 0.f) + __logf(1.f + __expf(-fabsf(x)))
                - (((t1 >> lane) & 1ULL) ? x : 0.f);
            s1 += l; se += ((e1 >> lane) & 1ULL) ? l : 0.f;
            x = p.z;
            l = fmaxf(x, 0.f) + __logf(1.f + __expf(-fabsf(x)))
                - (((t2 >> lane) & 1ULL) ? x : 0.f);
            s1 += l; se += ((e2 >> lane) & 1ULL) ? l : 0.f;
            x = p.w;
            l = fmaxf(x, 0.f) + __logf(1.f + __expf(-fabsf(x)))
                - (((t3 >> lane) & 1ULL) ? x : 0.f);
            s1 += l; se += ((e3 >> lane) & 1ULL) ? l : 0.f;
        }
    }

    // ---- reduce: wave shuffles, 8 waves via LDS, one atomic pair per block
    for (int off = 32; off > 0; off >>= 1) {
        s1 += __shfl_down(s1, off);
        se += __shfl_down(se, off);
    }
    if (lane == 0) { redS1[wid] = s1; redSe[wid] = se; }
    __syncthreads();
    if (tid == 0) {
        float S1 = 0.f, Se = 0.f;
        #pragma unroll
        for (int i = 0; i < 8; ++i) { S1 += redS1[i]; Se += redSe[i]; }
        atomicAdd(&dws[0], (double)S1);
        atomicAdd(&dws[1], (double)Se);
    }
}

// ---------------- fallback: old fused kernel (used if ws too small) ----------
__global__ __launch_bounds__(512) void bbl_main(
        const float* __restrict__ pred,
        const float* __restrict__ target,
        double* __restrict__ dws, unsigned* __restrict__ uws) {
    __shared__ u64 Bm[MAXROWS][WORDS];
    __shared__ u64 Vd[BAND][WORDS];
    __shared__ u64 Ve[BAND][WORDS];
    __shared__ u64 Em[BAND][WORDS];
    __shared__ float    redS1[8], redSe[8];
    __shared__ unsigned redMn[8], redMx[8];

    const int tid  = threadIdx.x;
    const int lane = tid & 63;
    const int wid  = tid >> 6;
    const int img  = blockIdx.x / NBANDS;
    const int r0   = (blockIdx.x % NBANDS) * BAND;
    const int hs   = max(r0 - HALO, 0);
    const int he   = min(r0 + BAND + HALO, IMG);
    const int nLoaded = he - hs;
    const size_t base = (size_t)img * IMG * IMG;

    float vmin = 3.4e38f, vmax = -3.4e38f;

    for (int lr = wid; lr < nLoaded; lr += 8) {
        const float4* rowp = (const float4*)(target + base + (size_t)(hs + lr) * IMG);
        #pragma unroll
        for (int it = 0; it < 4; ++it) {
            float4 v = rowp[it * 64 + lane];
            vmin = fminf(vmin, fminf(fminf(v.x, v.y), fminf(v.z, v.w)));
            vmax = fmaxf(vmax, fmaxf(fmaxf(v.x, v.y), fmaxf(v.z, v.w)));
            u64 b0 = __ballot(v.x > 0.5f);
            u64 b1 = __ballot(v.y > 0.5f);
            u64 b2 = __ballot(v.z > 0.5f);
            u64 b3 = __ballot(v.w > 0.5f);
            if (lane < 4) {
                u64 w = (lane == 0) ? b0 : (lane == 1) ? b1 : (lane == 2) ? b2 : b3;
                Bm[lr][it * 4 + lane] = w;
            }
        }
    }
    __syncthreads();
    {
        const int orow = tid >> 4, w = tid & 15;
        const int gr = r0 + orow;
        const int lo = max(gr - 2, 0), hi = min(gr + 2, IMG - 1);
        u64 vd = 0ULL, ve = ~0ULL;
        for (int g = lo; g <= hi; ++g) { u64 b = Bm[g - hs][w]; vd |= b; ve &= b; }
        Vd[orow][w] = vd; Ve[orow][w] = ve;
    }
    __syncthreads();
    {
        const int orow = tid >> 4, w = tid & 15;
        const int k = w & 3;
        u64 hd = Vd[orow][w], he_ = Ve[orow][w];
        #pragma unroll
        for (int dd = 0; dd < 4; ++dd) {
            const int delta = (dd < 2) ? dd - 2 : dd - 1;
            const int kp = k + delta;
            u64 td, te;
            if (kp >= 0 && kp <= 3) {
                td = Vd[orow][w + delta];
                te = Ve[orow][w + delta];
            } else if (kp > 3) {
                const int wi = w + delta - 4, wn = w + delta;
                u64 nd = (wn <= 15) ? Vd[orow][wn] : 0ULL;
                u64 ne = (wn <= 15) ? Ve[orow][wn] : ~0ULL;
                td = (Vd[orow][wi] >> 1) | (nd << 63);
                te = (Ve[orow][wi] >> 1) | (ne << 63);
            } else {
                const int wi = w + delta + 4, wn = w + delta;
                u64 nd = (wn >= 0) ? Vd[orow][wn] : 0ULL;
                u64 ne = (wn >= 0) ? Ve[orow][wn] : ~0ULL;
                td = (Vd[orow][wi] << 1) | (nd >> 63);
                te = (Ve[orow][wi] << 1) | (ne >> 63);
            }
            hd |= td; he_ &= te;
        }
        Em[orow][w] = hd & ~he_;
    }
    __syncthreads();

    float s1 = 0.f, se = 0.f;
    for (int orow = wid * 4; orow < wid * 4 + 4; ++orow) {
        const int gr = r0 + orow, lr = gr - hs;
        const float4* rowp = (const float4*)(pred + base + (size_t)gr * IMG);
        #pragma unroll
        for (int it = 0; it < 4; ++it) {
            float4 p = rowp[it * 64 + lane];
            u64 e0 = Em[orow][it * 4 + 0], e1 = Em[orow][it * 4 + 1];
            u64 e2 = Em[orow][it * 4 + 2], e3 = Em[orow][it * 4 + 3];
            u64 t0 = Bm[lr][it * 4 + 0],   t1 = Bm[lr][it * 4 + 1];
            u64 t2 = Bm[lr][it * 4 + 2],   t3 = Bm[lr][it * 4 + 3];
            float x, t, loss;
            x = p.x; t = (float)((unsigned)((t0 >> lane) & 1ULL));
            loss = fmaxf(x, 0.f) - x * t + __logf(1.f + __expf(-fabsf(x)));
            s1 += loss; se += ((e0 >> lane) & 1ULL) ? loss : 0.f;
            x = p.y; t = (float)((unsigned)((t1 >> lane) & 1ULL));
            loss = fmaxf(x, 0.f) - x * t + __logf(1.f + __expf(-fabsf(x)));
            s1 += loss; se += ((e1 >> lane) & 1ULL) ? loss : 0.f;
            x = p.z; t = (float)((unsigned)((t2 >> lane) & 1ULL));
            loss = fmaxf(x, 0.f) - x * t + __logf(1.f + __expf(-fabsf(x)));
            s1 += loss; se += ((e2 >> lane) & 1ULL) ? loss : 0.f;
            x = p.w; t = (float)((unsigned)((t3 >> lane) & 1ULL));
            loss = fmaxf(x, 0.f) - x * t + __logf(1.f + __expf(-fabsf(x)));
            s1 += loss; se += ((e3 >> lane) & 1ULL) ? loss : 0.f;
        }
    }

    for (int off = 32; off > 0; off >>= 1) {
        s1   += __shfl_down(s1, off);
        se   += __shfl_down(se, off);
        vmin  = fminf(vmin, __shfl_down(vmin, off));
        vmax  = fmaxf(vmax, __shfl_down(vmax, off));
    }
    if (lane == 0) {
        redS1[wid] = s1; redSe[wid] = se;
        redMn[wid] = encf(vmin); redMx[wid] = encf(vmax);
    }
    __syncthreads();
    if (tid == 0) {
        float S1 = 0.f, Se = 0.f; unsigned mn = 0xFFFFFFFFu, mx = 0u;
        #pragma unroll
        for (int i = 0; i < 8; ++i) {
            S1 += redS1[i]; Se += redSe[i];
            mn = min(mn, redMn[i]); mx = max(mx, redMx[i]);
        }
        atomicAdd(&dws[0], (double)S1);
        atomicAdd(&dws[1], (double)Se);
        atomicMin(&uws[0], mn);
        atomicMax(&uws[1], mx);
    }
}

__global__ void bbl_fin(const double* __restrict__ dws,
                        const unsigned* __restrict__ uws,
                        float* __restrict__ out) {
    if (threadIdx.x == 0) {
        float fmin = decf(uws[0]);
        float fmax = decf(uws[1]);
        bool cond = (fmax == 1.0f) && (fmin == 0.0f);
        double s = cond ? (dws[0] - 0.9 * dws[1]) : dws[0];
        out[0] = (float)(s / NTOT);
    }
}

extern "C" void kernel_launch(void* const* d_in, const int* in_sizes, int n_in,
                              void* d_out, int out_size, void* d_ws, size_t ws_size,
                              hipStream_t stream) {
    const float* pred   = (const float*)d_in[0];
    const float* target = (const float*)d_in[1];
    double*   dws = (double*)d_ws;
    unsigned* uws = (unsigned*)(dws + 2);
    float*    out = (float*)d_out;

    const size_t bits_off   = 64;
    const size_t bits_bytes = (size_t)NROWS * WORDS * sizeof(u64);   // 4 MB

    hipLaunchKernelGGL(bbl_init, dim3(1), dim3(64), 0, stream, dws, uws);
    if (ws_size >= bits_off + bits_bytes) {
        u64* bits = (u64*)((char*)d_ws + bits_off);
        hipLaunchKernelGGL(bbl_bits, dim3(2048), dim3(256), 0, stream,
                           target, bits, uws);
        hipLaunchKernelGGL(bbl_loss, dim3(NIMG * NBANDS), dim3(512), 0, stream,
                           pred, bits, dws);
    } else {
        hipLaunchKernelGGL(bbl_main, dim3(NIMG * NBANDS), dim3(512), 0, stream,
                           pred, target, dws, uws);
    }
    hipLaunchKernelGGL(bbl_fin, dim3(1), dim3(64), 0, stream, dws, uws, out);
}